// Round 9
// baseline (61.505 us; speedup 1.0000x reference)
//
#include <hip/hip_runtime.h>

#define NT 8192
#define DM 4096
#define NE 8
#define NSLOT 16384
#define CAP 1024
#define NBLK 2048   // K1 blocks: 4 tokens each
#define PROWS 2048  // partials rows

// ------------------------------------------------- fused logits + routing
// Block = 256 thr = 4 waves, handles 4 tokens. Wave w computes the partial
// logits of dim-quarter w (1024 dims) for all 4 tokens x 8 experts -> gate
// is read once per BLOCK (128 KB, halved vs 2-tok/wave), x quarter-rows are
// 4 independent loads/iter (ILP). Quarters combined via LDS; wave 0 does
// softmax/top-2/loss-partials for the 4 tokens.
__global__ __launch_bounds__(256, 4) void k_logits_route(
    const float* __restrict__ x, const float* __restrict__ gw,
    float* __restrict__ topk_p, unsigned char* __restrict__ flat_e,
    float* __restrict__ partials, int* __restrict__ counter) {
  const int tid = threadIdx.x;
  const int lane = tid & 63;
  const int wv = tid >> 6;            // dim-quarter 0..3
  const int blk = blockIdx.x;         // 0..2047
  const int t0 = blk * 4;
  if (blk == 0 && tid == 0) *counter = 0;  // stream-ordered reset for K2

  const float4* __restrict__ xv = (const float4*)x;
  const float4* __restrict__ gv = (const float4*)gw;
  const int qbase = wv * 256;         // float4 offset of my quarter

  float acc[4][8];
#pragma unroll
  for (int t = 0; t < 4; ++t)
#pragma unroll
    for (int e = 0; e < 8; ++e) acc[t][e] = 0.f;

#pragma unroll 2
  for (int c = 0; c < 4; ++c) {
    const int off = qbase + c * 64 + lane;
    float4 xr[4];
#pragma unroll
    for (int t = 0; t < 4; ++t) xr[t] = xv[(size_t)(t0 + t) * 1024 + off];
    float4 g4[8];
#pragma unroll
    for (int e = 0; e < 8; ++e) g4[e] = gv[e * 1024 + off];
#pragma unroll
    for (int t = 0; t < 4; ++t)
#pragma unroll
      for (int e = 0; e < 8; ++e) {
        acc[t][e] = fmaf(xr[t].x, g4[e].x, acc[t][e]);
        acc[t][e] = fmaf(xr[t].y, g4[e].y, acc[t][e]);
        acc[t][e] = fmaf(xr[t].z, g4[e].z, acc[t][e]);
        acc[t][e] = fmaf(xr[t].w, g4[e].w, acc[t][e]);
      }
  }

  // wave reduce: lane t*8+e holds this quarter's partial logit[t][e]
  float val = 0.f;
#pragma unroll
  for (int t = 0; t < 4; ++t)
#pragma unroll
    for (int e = 0; e < 8; ++e) {
      float v = acc[t][e];
#pragma unroll
      for (int s = 32; s > 0; s >>= 1) v += __shfl_xor(v, s, 64);
      if (lane == t * 8 + e) val = v;
    }
  __shared__ float red[4][32];
  if (lane < 32) red[wv][lane] = val;
  __syncthreads();

  if (wv == 0) {
    float tot = 0.f;
    if (lane < 32)
      tot = red[0][lane] + red[1][lane] + red[2][lane] + red[3][lane];
    // lane group g = lane>>3 handles token t0+g (valid for lane<32)
    const int g = lane >> 3;
    float l[8];
#pragma unroll
    for (int e = 0; e < 8; ++e) l[e] = __shfl(tot, g * 8 + e, 64);

    float m = l[0];
#pragma unroll
    for (int e = 1; e < 8; ++e) m = fmaxf(m, l[e]);
    float ex[8];
    float s = 0.f;
#pragma unroll
    for (int e = 0; e < 8; ++e) { ex[e] = expf(l[e] - m); s += ex[e]; }
    const float lse = m + logf(s);

    float b0 = l[0]; int i0 = 0;
#pragma unroll
    for (int e = 1; e < 8; ++e) if (l[e] > b0) { b0 = l[e]; i0 = e; }
    float b1 = -3.4e38f; int i1 = 0;
#pragma unroll
    for (int e = 0; e < 8; ++e) if (e != i0 && l[e] > b1) { b1 = l[e]; i1 = e; }

    const float t1 = expf(b1 - b0);
    const float ss = 1.f + t1;
    float p0 = 1.f / ss, p1 = t1 / ss;
    float s2 = p0 + p1;
    s2 = fmaxf(s2, 1e-8f);
    p0 /= s2; p1 /= s2;

    if (lane < 32 && (lane & 7) == 0) {
      const int tok = t0 + g;
      topk_p[2 * tok] = p0; topk_p[2 * tok + 1] = p1;
      flat_e[2 * tok] = (unsigned char)i0;
      flat_e[2 * tok + 1] = (unsigned char)i1;
    }

    // block partials: sum token-lanes {0,8,16,24}
    float vals[9];
#pragma unroll
    for (int e = 0; e < 8; ++e) vals[e] = ex[e] / s;
    vals[8] = lse * lse;
    float pout = 0.f;
#pragma unroll
    for (int mm = 0; mm < 9; ++mm) {
      const float v = vals[mm];
      const float sm = __shfl(v, 0, 64) + __shfl(v, 8, 64) +
                       __shfl(v, 16, 64) + __shfl(v, 24, 64);
      if (lane == mm) pout = sm;
    }
    if (lane < 9) partials[blk * 9 + lane] = pout;
  }
}

// ------------------------------------------- fused select + finalize + loss
// One block per expert. Single global read of (flat_e, topk_p) held in
// registers across count-prefix-compact; exact radix threshold if over
// capacity; writes this expert's output slots (disjoint), usage, lb product;
// last-arriving block (atomic counter) sums products in fixed order.
__global__ __launch_bounds__(256) void k_select_final(
    const float* __restrict__ flat_p, const unsigned char* __restrict__ flat_e,
    const float* __restrict__ partials, float* __restrict__ out,
    float* __restrict__ prod, float* __restrict__ zsum,
    int* __restrict__ counter) {
  const int e = blockIdx.x;
  const int t = threadIdx.x;
  const int lane = t & 63, wid = t >> 6;
  __shared__ unsigned int u_lds[NSLOT];     // 64 KB
  __shared__ unsigned short i_lds[NSLOT];   // 32 KB
  __shared__ int hist[4][1024];             // 16 KB
  __shared__ int wtot[4];
  __shared__ float fA[4], fZ[4];
  __shared__ int s_n, s_b, s_R2, s_cn, s_ti;
  __shared__ int s_cand[16];

  const uint4* __restrict__ e4p = (const uint4*)flat_e;
  const float4* __restrict__ p4p = (const float4*)flat_p;

  // ---- single global read: hold e-words and p-values in registers
  uint4 ev[4];
  float4 pv[4][4];
#pragma unroll
  for (int it = 0; it < 4; ++it) {
    const int vidx = t + it * 256;
    ev[it] = e4p[vidx];
#pragma unroll
    for (int q = 0; q < 4; ++q) pv[it][q] = p4p[vidx * 4 + q];
  }
  int mycnt = 0;
#pragma unroll
  for (int it = 0; it < 4; ++it) {
    const unsigned int w[4] = {ev[it].x, ev[it].y, ev[it].z, ev[it].w};
#pragma unroll
    for (int q = 0; q < 4; ++q)
#pragma unroll
      for (int b = 0; b < 4; ++b)
        mycnt += (((w[q] >> (8 * b)) & 0xffu) == (unsigned)e);
  }
  int pfx = mycnt;
#pragma unroll
  for (int off = 1; off < 64; off <<= 1) {
    const int tmp = __shfl_up(pfx, off, 64);
    if (lane >= off) pfx += tmp;
  }
  if (lane == 63) wtot[wid] = pfx;
  __syncthreads();
  int wbefore = 0;
  for (int w = 0; w < wid; ++w) wbefore += wtot[w];
  int pos = wbefore + pfx - mycnt;
  if (t == 255) s_n = wbefore + pfx;

  // ---- compact from registers
#pragma unroll
  for (int it = 0; it < 4; ++it) {
    const int vidx = t + it * 256;
    const unsigned int w[4] = {ev[it].x, ev[it].y, ev[it].z, ev[it].w};
#pragma unroll
    for (int q = 0; q < 4; ++q) {
      const float pf[4] = {pv[it][q].x, pv[it][q].y, pv[it][q].z, pv[it][q].w};
#pragma unroll
      for (int b = 0; b < 4; ++b) {
        if (((w[q] >> (8 * b)) & 0xffu) == (unsigned)e) {
          u_lds[pos] = __float_as_uint(pf[b]);
          i_lds[pos] = (unsigned short)(vidx * 16 + q * 4 + b);
          ++pos;
        }
      }
    }
  }
  __syncthreads();
  const int n = s_n;

  unsigned int tu = 0u;
  int ti_ = 0x7FFFFFFF;
  if (n > CAP) {
    // ---- radix on u (descending), 10 bits/pass, bits 29..0
    int R = CAP;
    unsigned int pref = 0;
    for (int pass = 0; pass < 3; ++pass) {
      const int shift = 20 - 10 * pass;
      for (int i = t; i < 4096; i += 256) ((int*)hist)[i] = 0;
      __syncthreads();
      for (int i = t; i < n; i += 256) {
        const unsigned int u = u_lds[i];
        if ((u >> (shift + 10)) == pref)
          atomicAdd(&hist[wid][(u >> shift) & 1023], 1);
      }
      __syncthreads();
      int c[4], chunk = 0;
#pragma unroll
      for (int k = 0; k < 4; ++k) {
        c[k] = hist[0][4 * t + k] + hist[1][4 * t + k] + hist[2][4 * t + k] +
               hist[3][4 * t + k];
        chunk += c[k];
      }
      int sfx = chunk;
#pragma unroll
      for (int off = 1; off < 64; off <<= 1) {
        const int tmp = __shfl_down(sfx, off, 64);
        if (lane + off < 64) sfx += tmp;
      }
      if (lane == 0) wtot[wid] = sfx;
      __syncthreads();
      int wafter = 0;
      for (int w = wid + 1; w < 4; ++w) wafter += wtot[w];
      const int after = sfx + wafter - chunk;
      if (after < R && after + chunk >= R) {
        int sx = after, bf = -1, rf = 0;
#pragma unroll
        for (int k = 3; k >= 0; --k) {
          if (bf < 0 && sx < R && sx + c[k] >= R) { bf = 4 * t + k; rf = R - sx; }
          sx += c[k];
        }
        s_b = bf; s_R2 = rf;
      }
      __syncthreads();
      pref = (pref << 10) | (unsigned int)s_b;
      R = s_R2;
      __syncthreads();
    }
    const unsigned int ustar = pref;

    // ---- ascending idx pass among u == ustar
    for (int i = t; i < 4096; i += 256) ((int*)hist)[i] = 0;
    if (t == 0) s_cn = 0;
    __syncthreads();
    for (int i = t; i < n; i += 256) {
      if (u_lds[i] == ustar) atomicAdd(&hist[wid][i_lds[i] >> 4], 1);
    }
    __syncthreads();
    int c[4], chunk = 0;
#pragma unroll
    for (int k = 0; k < 4; ++k) {
      c[k] = hist[0][4 * t + k] + hist[1][4 * t + k] + hist[2][4 * t + k] +
             hist[3][4 * t + k];
      chunk += c[k];
    }
    int pfa = chunk;
#pragma unroll
    for (int off = 1; off < 64; off <<= 1) {
      const int tmp = __shfl_up(pfa, off, 64);
      if (lane >= off) pfa += tmp;
    }
    if (lane == 63) wtot[wid] = pfa;
    __syncthreads();
    int wb = 0;
    for (int w = 0; w < wid; ++w) wb += wtot[w];
    const int before = wb + pfa - chunk;
    if (before < R && before + chunk >= R) {
      int cum = before, bf = -1, rf = 0;
#pragma unroll
      for (int k = 0; k < 4; ++k) {
        if (bf < 0 && cum < R && cum + c[k] >= R) { bf = 4 * t + k; rf = R - cum; }
        cum += c[k];
      }
      s_b = bf; s_R2 = rf;
    }
    __syncthreads();
    const int b3 = s_b, R4 = s_R2;
    for (int i = t; i < n; i += 256) {
      if (u_lds[i] == ustar && (i_lds[i] >> 4) == b3)
        s_cand[atomicAdd(&s_cn, 1)] = (int)i_lds[i];
    }
    __syncthreads();
    if (t == 0) {
      const int cn = s_cn;
      int ans = 0x7FFFFFFF;
      for (int a = 0; a < cn; ++a) {
        int r = 0;
        for (int b = 0; b < cn; ++b) r += (s_cand[b] < s_cand[a]);
        if (r == R4 - 1) ans = s_cand[a];
      }
      s_ti = ans;
    }
    __syncthreads();
    tu = ustar;
    ti_ = s_ti;
  }

  // ---- output phase: exactly this expert's slots (disjoint coverage)
  int myu = 0;
  for (int i = t; i < n; i += 256) {
    const unsigned int u = u_lds[i];
    const int idx = (int)i_lds[i];
    const bool kp = (u > tu) || (u == tu && idx <= ti_);
    out[idx] = kp ? (float)e : -1.0f;
    out[NSLOT + idx] = kp ? __uint_as_float(u) : 0.0f;
    myu += (kp && ((idx & 1) == 0)) ? 1 : 0;
  }
#pragma unroll
  for (int off = 32; off > 0; off >>= 1) myu += __shfl_xor(myu, off, 64);

  // ---- loss phase: ps[e] (+ z partial on block 0) over block-partials
  float a = 0.f, z = 0.f;
  for (int r = t; r < PROWS; r += 256) {
    a += partials[r * 9 + e];
    if (e == 0) z += partials[r * 9 + 8];
  }
#pragma unroll
  for (int off = 32; off > 0; off >>= 1) {
    a += __shfl_xor(a, off, 64);
    z += __shfl_xor(z, off, 64);
  }
  __syncthreads();  // before reusing wtot / writing fA,fZ
  if (lane == 0) { wtot[wid] = myu; fA[wid] = a; fZ[wid] = z; }
  __syncthreads();
  if (t == 0) {
    const int use = wtot[0] + wtot[1] + wtot[2] + wtot[3];
    const float ps_e = fA[0] + fA[1] + fA[2] + fA[3];
    out[2 * NSLOT + 2 + e] = (float)use;
    prod[e] = ps_e * (float)use;
    if (e == 0) *zsum = fZ[0] + fZ[1] + fZ[2] + fZ[3];
    __threadfence();
    const int old = atomicAdd(counter, 1);
    if (old == NE - 1) {  // last block: deterministic fixed-order sum
      __threadfence();
      float lb = 0.f;
#pragma unroll
      for (int q = 0; q < 8; ++q) lb += prod[q];
      out[2 * NSLOT]     = lb * (0.01f / (float)(NT * NE));
      out[2 * NSLOT + 1] = (*zsum / (float)NT) * 0.001f;
    }
  }
}

extern "C" void kernel_launch(void* const* d_in, const int* in_sizes, int n_in,
                              void* d_out, int out_size, void* d_ws, size_t ws_size,
                              hipStream_t stream) {
  const float* x  = (const float*)d_in[0];
  const float* gw = (const float*)d_in[1];
  float* out = (float*)d_out;
  char* ws = (char*)d_ws;

  float* topk_p         = (float*)(ws);                    // 65536 B
  unsigned char* flat_e = (unsigned char*)(ws + 65536);    // 16384 B
  float* partials       = (float*)(ws + 81920);            // 73728 B (2048*9*4)
  float* prod           = (float*)(ws + 155648);           // 32 B
  float* zsum           = (float*)(ws + 155680);           // 4 B
  int* counter          = (int*)(ws + 155712);             // 4 B

  hipLaunchKernelGGL(k_logits_route, dim3(NBLK), dim3(256), 0, stream, x, gw,
                     topk_p, flat_e, partials, counter);
  hipLaunchKernelGGL(k_select_final, dim3(8), dim3(256), 0, stream, topk_p,
                     flat_e, partials, out, prod, zsum, counter);
}